// Round 8
// baseline (2299.130 us; speedup 1.0000x reference)
//
#include <hip/hip_runtime.h>
#include <math.h>

#define QLEN 512
#define NB   64
#define DD   128
#define HH   256
#define WOUT 64
#define PI_F 3.14159265358979323846f

typedef __attribute__((ext_vector_type(8))) short bf16x8;
typedef __attribute__((ext_vector_type(4))) float f32x4;

__device__ __forceinline__ float sigmf(float x){ return 1.0f/(1.0f+expf(-x)); }
__device__ __forceinline__ float geluf(float x){ return 0.5f*x*(1.0f+erff(x*0.7071067811865476f)); }

// fp32 -> bf16 round-to-nearest-even
__device__ __forceinline__ unsigned short f2bf(float f){
    unsigned u = __float_as_uint(f);
    u += 0x7fffu + ((u >> 16) & 1u);
    return (unsigned short)(u >> 16);
}
__device__ __forceinline__ float bf2f(unsigned short h){
    return __uint_as_float(((unsigned)h) << 16);
}

// ---------------------------------------------------------------------------
// Fused weight-prep (1 launch). packw_elem: conv weights -> bf16x3 limbs in
// MFMA B-frag order (see conv_mfma_k). Also zeroes the rollout group-barrier
// counters (graph-replay-safe: re-zeroed every launch, before rollout runs).
__device__ __forceinline__ void packw_elem(const float* __restrict__ w,
                                           unsigned short* __restrict__ dst,
                                           int idx, int CIN, int COUT, int KS) {
    int j = idx & 7; int rest = idx >> 3;
    int lane = rest & 63; rest >>= 6;
    int NT = COUT >> 4;
    int nt = rest % NT; int kt = rest / NT;
    int k = kt*32 + (lane >> 4)*8 + j;
    int cout = nt*16 + (lane & 15);
    int tap = k / CIN, ci = k - tap*CIN;
    float v = w[((size_t)cout*CIN + ci)*KS + tap];
    unsigned short h0 = f2bf(v);  float r = v - bf2f(h0);
    unsigned short h1 = f2bf(r);  r -= bf2f(h1);
    unsigned short h2 = f2bf(r);
    int SZ = KS*CIN*COUT;
    dst[idx] = h0; dst[SZ + idx] = h1; dst[2*SZ + idx] = h2;
}
__global__ __launch_bounds__(256) void prep_k(
    const float* __restrict__ inp_w, const float* __restrict__ b0c1w,
    const float* __restrict__ b0c2w, const float* __restrict__ b1c1w,
    const float* __restrict__ b1c2w, const float* __restrict__ gainw,
    unsigned short* __restrict__ Pinp,  unsigned short* __restrict__ Pb0c1,
    unsigned short* __restrict__ Pb0c2, unsigned short* __restrict__ Pb1c1,
    unsigned short* __restrict__ Pb1c2, unsigned short* __restrict__ Pgain,
    unsigned* __restrict__ bars)
{
    int idx = blockIdx.x*256 + threadIdx.x;
    if      (idx <   98304) packw_elem(inp_w, Pinp,  idx,          384, 256, 1);
    else if (idx <  294912) packw_elem(b0c1w, Pb0c1, idx -  98304, 256, 256, 3);
    else if (idx <  491520) packw_elem(b0c2w, Pb0c2, idx - 294912, 256, 256, 3);
    else if (idx <  688128) packw_elem(b1c1w, Pb1c1, idx - 491520, 256, 256, 3);
    else if (idx <  884736) packw_elem(b1c2w, Pb1c2, idx - 688128, 256, 256, 3);
    else if (idx <  917504) packw_elem(gainw, Pgain, idx - 884736, 256, 128, 1);
    else if (idx <  917632) bars[idx - 917504] = 0u;
}

// ---------------------------------------------------------------------------
// Conv-as-GEMM via bf16x3 MFMA (6 products = fp32-equivalent). Proven r4:
// passes at absmax 0.125. Unchanged.
template<int CIN, int COUT, int KS, int DIL, int ACT, int FEATS, int TM>
__global__ __launch_bounds__(256, 2) void conv_mfma_k(
    const float* __restrict__ X, const unsigned short* __restrict__ W,
    const float* __restrict__ bias, float* __restrict__ Y)
{
    constexpr int HALO = (KS == 3) ? DIL : 0;
    constexpr int ROWS = TM + 2*HALO;
    constexpr int CINP = CIN + 8;
    constexpr int MF   = TM/16;
    constexpr int NF   = COUT/64;
    constexpr int KT   = (KS*CIN)/32;
    constexpr int TPC  = CIN/32;
    constexpr int WSZ  = KS*CIN*COUT;

    __shared__ __align__(16) unsigned short As[3][ROWS][CINP];

    const int b   = blockIdx.y;
    const int t0  = blockIdx.x * TM;
    const int tid = threadIdx.x;

    if constexpr (FEATS) {
        for (int idx = tid; idx < TM*DD; idx += 256) {
            int r = idx >> 7, d = idx & (DD-1);
            int t = t0 + r;
            const float* xr = X + ((size_t)b*QLEN + t)*DD + d;
            float x    = xr[0];
            float xm1  = (t >= 1) ? xr[-DD]   : 0.f;
            float xm2  = (t >= 2) ? xr[-2*DD] : 0.f;
            float dy   = (t >= 1) ? (x - xm1)   : 0.f;
            float dym1 = (t >= 2) ? (xm1 - xm2) : 0.f;
            float ddy  = (t >= 1) ? (dy - dym1) : 0.f;
            float vals[3] = {x, dy, ddy};
            #pragma unroll
            for (int f = 0; f < 3; ++f) {
                float v = vals[f];
                unsigned short h0 = f2bf(v);  float rr = v - bf2f(h0);
                unsigned short h1 = f2bf(rr); rr -= bf2f(h1);
                unsigned short h2 = f2bf(rr);
                As[0][r][f*DD + d] = h0;
                As[1][r][f*DD + d] = h1;
                As[2][r][f*DD + d] = h2;
            }
        }
    } else {
        for (int idx = tid; idx < ROWS*(CIN/4); idx += 256) {
            int r = idx / (CIN/4), c4 = idx % (CIN/4);
            int gr = t0 + r - HALO;
            gr = gr < 0 ? 0 : (gr > QLEN-1 ? QLEN-1 : gr);
            float4 v = reinterpret_cast<const float4*>(X + ((size_t)b*QLEN + gr)*CIN)[c4];
            float vv[4] = {v.x, v.y, v.z, v.w};
            ushort4 s0, s1, s2;
            unsigned short* q0 = (unsigned short*)&s0;
            unsigned short* q1 = (unsigned short*)&s1;
            unsigned short* q2 = (unsigned short*)&s2;
            #pragma unroll
            for (int e = 0; e < 4; ++e) {
                float v1 = vv[e];
                unsigned short h0 = f2bf(v1);  float rr = v1 - bf2f(h0);
                unsigned short h1 = f2bf(rr);  rr -= bf2f(h1);
                q0[e] = h0; q1[e] = h1; q2[e] = f2bf(rr);
            }
            *reinterpret_cast<ushort4*>(&As[0][r][c4*4]) = s0;
            *reinterpret_cast<ushort4*>(&As[1][r][c4*4]) = s1;
            *reinterpret_cast<ushort4*>(&As[2][r][c4*4]) = s2;
        }
    }
    __syncthreads();

    const int wv = tid >> 6, l = tid & 63;
    const int lr = l & 15, lk = l >> 4;

    f32x4 acc[MF][NF];
    #pragma unroll
    for (int m = 0; m < MF; ++m)
        #pragma unroll
        for (int n = 0; n < NF; ++n)
            #pragma unroll
            for (int i = 0; i < 4; ++i) acc[m][n][i] = 0.f;

    auto loadB = [&](int kt, bf16x8 (&Bf)[NF][3]) {
        #pragma unroll
        for (int n = 0; n < NF; ++n) {
            const unsigned short* p =
                W + ((size_t)(kt*(COUT/16) + wv*NF + n)*64 + l)*8;
            #pragma unroll
            for (int q = 0; q < 3; ++q)
                Bf[n][q] = *reinterpret_cast<const bf16x8*>(p + (size_t)q*WSZ);
        }
    };
    auto comp = [&](int kt, bf16x8 (&Bf)[NF][3]) {
        const int tap = kt / TPC;
        const int kin = (kt % TPC)*32 + lk*8;
        bf16x8 A[MF][3];
        #pragma unroll
        for (int m = 0; m < MF; ++m) {
            const int row = m*16 + lr + tap*DIL;
            #pragma unroll
            for (int q = 0; q < 3; ++q)
                A[m][q] = *reinterpret_cast<const bf16x8*>(&As[q][row][kin]);
        }
        #pragma unroll
        for (int m = 0; m < MF; ++m)
            #pragma unroll
            for (int n = 0; n < NF; ++n) {
                f32x4 c = acc[m][n];
                c = __builtin_amdgcn_mfma_f32_16x16x32_bf16(A[m][0], Bf[n][0], c, 0,0,0);
                c = __builtin_amdgcn_mfma_f32_16x16x32_bf16(A[m][0], Bf[n][1], c, 0,0,0);
                c = __builtin_amdgcn_mfma_f32_16x16x32_bf16(A[m][1], Bf[n][0], c, 0,0,0);
                c = __builtin_amdgcn_mfma_f32_16x16x32_bf16(A[m][0], Bf[n][2], c, 0,0,0);
                c = __builtin_amdgcn_mfma_f32_16x16x32_bf16(A[m][1], Bf[n][1], c, 0,0,0);
                c = __builtin_amdgcn_mfma_f32_16x16x32_bf16(A[m][2], Bf[n][0], c, 0,0,0);
                acc[m][n] = c;
            }
    };

    bf16x8 B0[NF][3], B1[NF][3];
    loadB(0, B0);
    #pragma unroll 1
    for (int kt = 0; kt < KT; kt += 2) {
        loadB(kt+1, B1);
        comp(kt, B0);
        if (kt + 2 < KT) loadB(kt+2, B0);
        comp(kt+1, B1);
    }

    #pragma unroll
    for (int n = 0; n < NF; ++n) {
        const int col = (wv*NF + n)*16 + lr;
        const float bv = bias[col];
        #pragma unroll
        for (int m = 0; m < MF; ++m) {
            #pragma unroll
            for (int i = 0; i < 4; ++i) {
                float v = acc[m][n][i] + bv;
                if constexpr (ACT == 1) v = geluf(v);
                if constexpr (ACT == 2) v = sigmf(v);
                Y[((size_t)b*QLEN + t0 + m*16 + lk*4 + i)*COUT + col] = v;
            }
        }
    }
}

// ---------------------------------------------------------------------------
__global__ __launch_bounds__(256) void ln_k(
    const float* __restrict__ X, const float* __restrict__ R,
    const float* __restrict__ w, const float* __restrict__ b,
    float* __restrict__ Y)
{
    int row  = blockIdx.x*4 + (threadIdx.x >> 6);
    int lane = threadIdx.x & 63;
    float4 v = reinterpret_cast<const float4*>(X + (size_t)row*HH)[lane];
    float4 rv = reinterpret_cast<const float4*>(R + (size_t)row*HH)[lane];
    v.x += rv.x; v.y += rv.y; v.z += rv.z; v.w += rv.w;
    float s = v.x + v.y + v.z + v.w;
    #pragma unroll
    for (int off = 32; off > 0; off >>= 1) s += __shfl_xor(s, off);
    float m = s * (1.0f/HH);
    float dx=v.x-m, dy=v.y-m, dz=v.z-m, dw=v.w-m;
    float q = dx*dx + dy*dy + dz*dz + dw*dw;
    #pragma unroll
    for (int off = 32; off > 0; off >>= 1) q += __shfl_xor(q, off);
    float inv = rsqrtf(q*(1.0f/HH) + 1e-5f);
    float4 wv = reinterpret_cast<const float4*>(w)[lane];
    float4 bv = reinterpret_cast<const float4*>(b)[lane];
    float4 o;
    o.x = dx*inv*wv.x + bv.x;
    o.y = dy*inv*wv.y + bv.y;
    o.z = dz*inv*wv.z + bv.z;
    o.w = dw*inv*wv.w + bv.w;
    reinterpret_cast<float4*>(Y + (size_t)row*HH)[lane] = o;
}

// ---------------------------------------------------------------------------
__global__ __launch_bounds__(256) void ln_rp_k(
    const float* __restrict__ X, const float* __restrict__ w, const float* __restrict__ b,
    const float* __restrict__ rpw, const float* __restrict__ rpb,
    float* __restrict__ Y, float* __restrict__ rho, float* __restrict__ phi)
{
    int row  = blockIdx.x*4 + (threadIdx.x >> 6);
    int lane = threadIdx.x & 63;
    float4 v = reinterpret_cast<const float4*>(X + (size_t)row*HH)[lane];
    float s = v.x + v.y + v.z + v.w;
    #pragma unroll
    for (int off = 32; off > 0; off >>= 1) s += __shfl_xor(s, off);
    float m = s * (1.0f/HH);
    float dx=v.x-m, dy=v.y-m, dz=v.z-m, dw=v.w-m;
    float q = dx*dx + dy*dy + dz*dz + dw*dw;
    #pragma unroll
    for (int off = 32; off > 0; off >>= 1) q += __shfl_xor(q, off);
    float inv = rsqrtf(q*(1.0f/HH) + 1e-5f);
    float4 wv = reinterpret_cast<const float4*>(w)[lane];
    float4 bv = reinterpret_cast<const float4*>(b)[lane];
    float4 o;
    o.x = dx*inv*wv.x + bv.x;
    o.y = dy*inv*wv.y + bv.y;
    o.z = dz*inv*wv.z + bv.z;
    o.w = dw*inv*wv.w + bv.w;
    reinterpret_cast<float4*>(Y + (size_t)row*HH)[lane] = o;

    float4 w0 = reinterpret_cast<const float4*>(rpw)[lane];
    float4 w1 = reinterpret_cast<const float4*>(rpw + HH)[lane];
    float d0 = o.x*w0.x + o.y*w0.y + o.z*w0.z + o.w*w0.w;
    float d1 = o.x*w1.x + o.y*w1.y + o.z*w1.z + o.w*w1.w;
    #pragma unroll
    for (int off = 32; off > 0; off >>= 1) { d0 += __shfl_xor(d0, off); d1 += __shfl_xor(d1, off); }
    if (lane == 0) {
        rho[row] = 1.25f * sigmf(d0 + rpb[0]);
        phi[row] = PI_F * tanhf(d1 + rpb[1]);
    }
}

// ---------------------------------------------------------------------------
__global__ __launch_bounds__(64) void kalman_k(
    const float* __restrict__ Xin, const float* __restrict__ Kg,
    const float* __restrict__ rho_a, const float* __restrict__ phi_a,
    float* __restrict__ xpost)
{
    int b = blockIdx.x, l = threadIdx.x;
    const float* xb = Xin + (size_t)b*QLEN*DD;
    float re = xb[l], im = xb[64 + l];

    float rho_c = rho_a[b*QLEN], phi_c = phi_a[b*QLEN];
    const float* kg0 = Kg + (size_t)b*QLEN*DD;
    float kr_c = kg0[l], ki_c = kg0[64 + l];
    float y0_c = xb[l],  y1_c = xb[64 + l];

    for (int t = 0; t < QLEN; ++t) {
        float rho_n = 0.f, phi_n = 0.f, kr_n = 0.f, ki_n = 0.f, y0_n = 0.f, y1_n = 0.f;
        if (t + 1 < QLEN) {
            rho_n = rho_a[b*QLEN + t + 1];
            phi_n = phi_a[b*QLEN + t + 1];
            const float* kg = Kg + ((size_t)b*QLEN + t + 1)*DD;
            const float* yr = xb + (size_t)(t + 1)*DD;
            kr_n = kg[l]; ki_n = kg[64 + l];
            y0_n = yr[l]; y1_n = yr[64 + l];
        }
        float sn, cs; sincosf(phi_c, &sn, &cs);
        float pr = rho_c*(cs*re - sn*im);
        float pi = rho_c*(sn*re + cs*im);
        re = pr + kr_c*(y0_c - pr);
        im = pi + ki_c*(y1_c - pi);
        rho_c = rho_n; phi_c = phi_n; kr_c = kr_n; ki_c = ki_n; y0_c = y0_n; y1_c = y1_n;
    }
    xpost[b*DD + l]      = re;
    xpost[b*DD + 64 + l] = im;
}

// ---------------------------------------------------------------------------
// Rollout v7 — cooperative, LDS-resident weight slices.
// r4 PMC: rollout_k5 = 1058us, VALUBusy 9%, 119 GB/s/CU == per-CU L2 port
// limit on the 1.92 MB/step weight re-stream. Fix: 4 groups x 32 blocks;
// each block keeps an fp32 weight slice (8 z-rows Wri, 24 gate rows Wih/Whh,
// ~111 KB) in LDS -> zero weight streaming. Cross-block state (z, h_raw)
// via global + group barrier; LN/rho/phi/rotate recomputed redundantly per
// block (deterministic -> replicas identical) so only 2 barriers/step.
// Weights in LDS are immune to the L2-invalidating agent fences that killed
// the earlier multi-block attempt (FETCH 7.8MB->2.75GB).
// Barrier: monotone ticket counter (never resets -> stale reads can only
// over-wait, never early-exit). Zeroed by prep_k each launch.
// LDS total 110,976 B -> 1 block/CU; 128 blocks co-resident on 256 CUs.
#define GBLK 32
#define BPG  16
#define ZSL  8
#define GSL  24

__device__ __forceinline__ void gbar(unsigned* cnt, unsigned target) {
    __syncthreads();
    if (threadIdx.x == 0) {
        unsigned a = __hip_atomic_fetch_add(cnt, 1u, __ATOMIC_ACQ_REL, __HIP_MEMORY_SCOPE_AGENT);
        if (a != target - 1u) {
            while (__hip_atomic_load(cnt, __ATOMIC_ACQUIRE, __HIP_MEMORY_SCOPE_AGENT) < target)
                __builtin_amdgcn_s_sleep(2);
        }
    }
    __syncthreads();
}

__global__ __launch_bounds__(1024) void rollout_k7(
    const float* __restrict__ Hs, const float* __restrict__ xpost,
    const float* __restrict__ riw, const float* __restrict__ rib,
    const float* __restrict__ wih, const float* __restrict__ whh,
    const float* __restrict__ bih, const float* __restrict__ bhh,
    const float* __restrict__ lnw, const float* __restrict__ lnb,
    const float* __restrict__ rpw, const float* __restrict__ rpb,
    float* __restrict__ zbuf, float* __restrict__ hraw,
    unsigned* __restrict__ bars, float* __restrict__ out)
{
    __shared__ __align__(16) float Wri_s[ZSL][388];
    __shared__ __align__(16) float Wih_s[GSL][260];
    __shared__ __align__(16) float Whh_s[GSL][260];
    __shared__ __align__(16) float hcs[BPG][388];   // [h_r(256); curr(128)] per batch
    __shared__ __align__(16) float sbuf[BPG][260];  // staging: hraw (head) / z (B)
    __shared__ float ghs[GSL][BPG];
    __shared__ float gis[GSL][BPG];
    __shared__ float lnw_s[256], lnb_s[256], rw0_s[256], rw1_s[256];

    const int tid = threadIdx.x;
    const int g   = blockIdx.x >> 5;    // group
    const int j   = blockIdx.x & 31;    // slice index in group
    const int o0  = j * ZSL;            // owned h/z dim base
    const int b0  = g * BPG;            // batch base
    unsigned* bcnt = bars + g*32;

    // ---- prologue: weight slices + biases -> LDS; prime hcs
    for (int i = tid; i < ZSL*384; i += 1024) {
        int r = i / 384, k = i - r*384;
        Wri_s[r][k] = riw[(size_t)(o0 + r)*384 + k];
    }
    for (int i = tid; i < GSL*256; i += 1024) {
        int r = i >> 8, k = i & 255;
        int gate = r >> 3, oo = r & 7;
        size_t grow = (size_t)(gate*256 + o0 + oo)*256 + k;
        Wih_s[r][k] = wih[grow];
        Whh_s[r][k] = whh[grow];
    }
    if (tid < 256) {
        lnw_s[tid] = lnw[tid]; lnb_s[tid] = lnb[tid];
        rw0_s[tid] = rpw[tid]; rw1_s[tid] = rpw[256 + tid];
    }
    for (int i = tid; i < BPG*256; i += 1024) {
        int b = i >> 8, c = i & 255;
        hcs[b][c] = Hs[((size_t)(b0 + b)*QLEN + (QLEN-1))*HH + c];
    }
    for (int i = tid; i < BPG*128; i += 1024) {
        int b = i >> 7, c = i & 127;
        hcs[b][256 + c] = xpost[(b0 + b)*DD + c];
    }

    // per-thread role constants (loop-invariant)
    const int zoo = tid & 7, zb2 = tid >> 3;           // tid<64: z tile (2 batches)
    const int u   = tid - 64;                          // tid in [64,160): gh tile (4 batches)
    const int gbt = (u >= 0) ? (u / 24) : 0;
    const int gr  = (u >= 0) ? (u - gbt*24) : 0;
    const int bbt = tid / 24, br = tid - bbt*24;       // tid<96: gi tile (4 batches)
    float ribv = 0.f, bhhv = 0.f, bihv = 0.f;
    if (tid < 64)               ribv = rib[o0 + zoo];
    if (tid >= 64 && tid < 160) bhhv = bhh[(gr >> 3)*256 + o0 + (gr & 7)];
    if (tid < 96)               bihv = bih[(br >> 3)*256 + o0 + (br & 7)];
    const float rpb0 = rpb[0], rpb1 = rpb[1];
    __syncthreads();

    unsigned nbar = 0;

    for (int s = 0; ; ++s) {
        if (s > 0) {
            // ---- head (redundant per block): LN(h_raw)->h_r; rho/phi; rotate curr
            {
                int b = tid >> 6, c4 = tid & 63;
                *reinterpret_cast<float4*>(&sbuf[b][c4*4]) =
                    *reinterpret_cast<const float4*>(hraw + (size_t)(b0 + b)*256 + c4*4);
            }
            __syncthreads();
            {
                const int b = tid >> 6, l = tid & 63;  // wave b handles batch b
                float4 v = *reinterpret_cast<const float4*>(&sbuf[b][l*4]);
                float sm = v.x + v.y + v.z + v.w;
                #pragma unroll
                for (int off = 32; off > 0; off >>= 1) sm += __shfl_xor(sm, off);
                float m = sm * (1.0f/HH);
                float dx=v.x-m, dy=v.y-m, dz=v.z-m, dw=v.w-m;
                float q = dx*dx + dy*dy + dz*dz + dw*dw;
                #pragma unroll
                for (int off = 32; off > 0; off >>= 1) q += __shfl_xor(q, off);
                float inv = rsqrtf(q*(1.0f/HH) + 1e-5f);
                float h0 = dx*inv*lnw_s[l*4+0] + lnb_s[l*4+0];
                float h1 = dy*inv*lnw_s[l*4+1] + lnb_s[l*4+1];
                float h2 = dz*inv*lnw_s[l*4+2] + lnb_s[l*4+2];
                float h3 = dw*inv*lnw_s[l*4+3] + lnb_s[l*4+3];
                float4 hv; hv.x=h0; hv.y=h1; hv.z=h2; hv.w=h3;
                *reinterpret_cast<float4*>(&hcs[b][l*4]) = hv;
                float d0 = h0*rw0_s[l*4+0] + h1*rw0_s[l*4+1] + h2*rw0_s[l*4+2] + h3*rw0_s[l*4+3];
                float d1 = h0*rw1_s[l*4+0] + h1*rw1_s[l*4+1] + h2*rw1_s[l*4+2] + h3*rw1_s[l*4+3];
                #pragma unroll
                for (int off = 32; off > 0; off >>= 1) { d0 += __shfl_xor(d0, off); d1 += __shfl_xor(d1, off); }
                float rho = 1.25f * sigmf(d0 + rpb0);
                float phi = PI_F * tanhf(d1 + rpb1);
                float sn, cs; sincosf(phi, &sn, &cs);
                float re = hcs[b][256 + l], im = hcs[b][320 + l];
                float nr = rho*(cs*re - sn*im);
                float ni = rho*(sn*re + cs*im);
                hcs[b][256 + l] = nr; hcs[b][320 + l] = ni;
                if (j == b) {   // owner writes output for its batch
                    float* ob = out + ((size_t)(b0 + b)*WOUT + (s-1))*DD;
                    ob[l] = nr; ob[64 + l] = ni;
                }
            }
            __syncthreads();
            if (s == WOUT) break;
        }

        // ---- phase A: z-slice (Wri) + gh-slice (Whh), all from LDS
        if (tid < 64) {
            const int bb = zb2*2;
            float a0 = 0.f, a1 = 0.f;
            for (int kq = 0; kq < 96; ++kq) {
                float4 w  = *reinterpret_cast<const float4*>(&Wri_s[zoo][kq*4]);
                float4 x0 = *reinterpret_cast<const float4*>(&hcs[bb  ][kq*4]);
                float4 x1 = *reinterpret_cast<const float4*>(&hcs[bb+1][kq*4]);
                a0 = fmaf(w.x,x0.x,a0); a0 = fmaf(w.y,x0.y,a0); a0 = fmaf(w.z,x0.z,a0); a0 = fmaf(w.w,x0.w,a0);
                a1 = fmaf(w.x,x1.x,a1); a1 = fmaf(w.y,x1.y,a1); a1 = fmaf(w.z,x1.z,a1); a1 = fmaf(w.w,x1.w,a1);
            }
            zbuf[(size_t)(b0+bb  )*256 + o0 + zoo] = tanhf(a0 + ribv);
            zbuf[(size_t)(b0+bb+1)*256 + o0 + zoo] = tanhf(a1 + ribv);
        } else if (tid < 160) {
            const int bb = gbt*4;
            float a0=0.f, a1=0.f, a2=0.f, a3=0.f;
            for (int kq = 0; kq < 64; ++kq) {
                float4 w  = *reinterpret_cast<const float4*>(&Whh_s[gr][kq*4]);
                float4 x0 = *reinterpret_cast<const float4*>(&hcs[bb+0][kq*4]);
                float4 x1 = *reinterpret_cast<const float4*>(&hcs[bb+1][kq*4]);
                float4 x2 = *reinterpret_cast<const float4*>(&hcs[bb+2][kq*4]);
                float4 x3 = *reinterpret_cast<const float4*>(&hcs[bb+3][kq*4]);
                a0 = fmaf(w.x,x0.x,a0); a0 = fmaf(w.y,x0.y,a0); a0 = fmaf(w.z,x0.z,a0); a0 = fmaf(w.w,x0.w,a0);
                a1 = fmaf(w.x,x1.x,a1); a1 = fmaf(w.y,x1.y,a1); a1 = fmaf(w.z,x1.z,a1); a1 = fmaf(w.w,x1.w,a1);
                a2 = fmaf(w.x,x2.x,a2); a2 = fmaf(w.y,x2.y,a2); a2 = fmaf(w.z,x2.z,a2); a2 = fmaf(w.w,x2.w,a2);
                a3 = fmaf(w.x,x3.x,a3); a3 = fmaf(w.y,x3.y,a3); a3 = fmaf(w.z,x3.z,a3); a3 = fmaf(w.w,x3.w,a3);
            }
            ghs[gr][bb+0] = a0 + bhhv; ghs[gr][bb+1] = a1 + bhhv;
            ghs[gr][bb+2] = a2 + bhhv; ghs[gr][bb+3] = a3 + bhhv;
        }
        nbar++; gbar(bcnt, nbar*GBLK);

        // ---- phase B: gi-slice (Wih over z) + GRU combine -> h_raw slice
        {
            int b = tid >> 6, c4 = tid & 63;
            *reinterpret_cast<float4*>(&sbuf[b][c4*4]) =
                *reinterpret_cast<const float4*>(zbuf + (size_t)(b0 + b)*256 + c4*4);
        }
        __syncthreads();
        if (tid < 96) {
            const int bb = bbt*4;
            float a0=0.f, a1=0.f, a2=0.f, a3=0.f;
            for (int kq = 0; kq < 64; ++kq) {
                float4 w  = *reinterpret_cast<const float4*>(&Wih_s[br][kq*4]);
                float4 x0 = *reinterpret_cast<const float4*>(&sbuf[bb+0][kq*4]);
                float4 x1 = *reinterpret_cast<const float4*>(&sbuf[bb+1][kq*4]);
                float4 x2 = *reinterpret_cast<const float4*>(&sbuf[bb+2][kq*4]);
                float4 x3 = *reinterpret_cast<const float4*>(&sbuf[bb+3][kq*4]);
                a0 = fmaf(w.x,x0.x,a0); a0 = fmaf(w.y,x0.y,a0); a0 = fmaf(w.z,x0.z,a0); a0 = fmaf(w.w,x0.w,a0);
                a1 = fmaf(w.x,x1.x,a1); a1 = fmaf(w.y,x1.y,a1); a1 = fmaf(w.z,x1.z,a1); a1 = fmaf(w.w,x1.w,a1);
                a2 = fmaf(w.x,x2.x,a2); a2 = fmaf(w.y,x2.y,a2); a2 = fmaf(w.z,x2.z,a2); a2 = fmaf(w.w,x2.w,a2);
                a3 = fmaf(w.x,x3.x,a3); a3 = fmaf(w.y,x3.y,a3); a3 = fmaf(w.z,x3.z,a3); a3 = fmaf(w.w,x3.w,a3);
            }
            gis[br][bb+0] = a0 + bihv; gis[br][bb+1] = a1 + bihv;
            gis[br][bb+2] = a2 + bihv; gis[br][bb+3] = a3 + bihv;
        }
        __syncthreads();
        if (tid < 128) {
            const int oo = tid & 7, b = tid >> 3;
            float G0 = gis[oo][b], G1 = gis[8+oo][b], G2 = gis[16+oo][b];
            float E0 = ghs[oo][b], E1 = ghs[8+oo][b], E2 = ghs[16+oo][b];
            float r  = sigmf(G0 + E0);
            float zg = sigmf(G1 + E1);
            float n  = tanhf(G2 + r*E2);
            hraw[(size_t)(b0 + b)*256 + o0 + oo] = (1.0f - zg)*n + zg*hcs[b][o0 + oo];
        }
        nbar++; gbar(bcnt, nbar*GBLK);
    }
}

// ---------------------------------------------------------------------------
extern "C" void kernel_launch(void* const* d_in, const int* in_sizes, int n_in,
                              void* d_out, int out_size, void* d_ws, size_t ws_size,
                              hipStream_t stream)
{
    const float* x_in   = (const float*)d_in[0];
    const float* inp_w  = (const float*)d_in[2];
    const float* inp_b  = (const float*)d_in[3];
    const float* b0c1w  = (const float*)d_in[4];
    const float* b0c1b  = (const float*)d_in[5];
    const float* b0c2w  = (const float*)d_in[6];
    const float* b0c2b  = (const float*)d_in[7];
    const float* b0lnw  = (const float*)d_in[8];
    const float* b0lnb  = (const float*)d_in[9];
    const float* b1c1w  = (const float*)d_in[10];
    const float* b1c1b  = (const float*)d_in[11];
    const float* b1c2w  = (const float*)d_in[12];
    const float* b1c2b  = (const float*)d_in[13];
    const float* b1lnw  = (const float*)d_in[14];
    const float* b1lnb  = (const float*)d_in[15];
    const float* olnw   = (const float*)d_in[16];
    const float* olnb   = (const float*)d_in[17];
    const float* gainw  = (const float*)d_in[18];
    const float* gainb  = (const float*)d_in[19];
    const float* rpw    = (const float*)d_in[20];
    const float* rpb    = (const float*)d_in[21];
    const float* riw    = (const float*)d_in[22];
    const float* rib    = (const float*)d_in[23];
    const float* wih    = (const float*)d_in[24];
    const float* whh    = (const float*)d_in[25];
    const float* bih    = (const float*)d_in[26];
    const float* bhh    = (const float*)d_in[27];
    const float* rlnw   = (const float*)d_in[28];
    const float* rlnb   = (const float*)d_in[29];
    const float* rprw   = (const float*)d_in[30];
    const float* rprb   = (const float*)d_in[31];
    float* out = (float*)d_out;

    // workspace layout (floats)
    float* ws   = (float*)d_ws;
    float* buf0 = ws;                    // 8388608
    float* buf1 = ws +  8388608;         // 8388608
    float* buf2 = ws + 16777216;         // 8388608
    float* Kg    = buf2;                 // 4194304 (buf2 dead by then)
    float* rhoA  = buf2 + 4194304;       // 32768
    float* phiA  = rhoA + 32768;         // 32768
    float* xpost = phiA + 32768;         // 8192
    float* wts   = ws + 25165824;
    // bf16x3 packed conv weights (ushort counts):
    unsigned short* Pinp  = (unsigned short*)wts;   // 3*98304  = 294912
    unsigned short* Pb0c1 = Pinp  + 294912;         // 3*196608 = 589824
    unsigned short* Pb0c2 = Pb0c1 + 589824;
    unsigned short* Pb1c1 = Pb0c2 + 589824;
    unsigned short* Pb1c2 = Pb1c1 + 589824;
    unsigned short* Pgain = Pb1c2 + 589824;         // 3*32768 = 98304
    // rollout exchange buffers + barriers (after packed weights = 1376256 floats)
    float* zbufp = wts + 1376256;                   // 16384
    float* hrawp = zbufp + 16384;                   // 16384
    unsigned* barsp = (unsigned*)(hrawp + 16384);   // 128 words

    // ---- fused weight prep + barrier zeroing (1 launch)
    prep_k<<<3585, 256, 0, stream>>>(inp_w, b0c1w, b0c2w, b1c1w, b1c2w, gainw,
                                     Pinp, Pb0c1, Pb0c2, Pb1c1, Pb1c2, Pgain,
                                     barsp);

    dim3 cg16(QLEN/16, NB);
    dim3 cg32(QLEN/32, NB);

    // ---- input projection (feats built on the fly): x_in -> buf0
    conv_mfma_k<384,256,1,1,0,1,16><<<cg16, 256, 0, stream>>>(x_in, Pinp, inp_b, buf0);

    // ---- block 0 (dil=1)
    conv_mfma_k<256,256,3,1,1,0,32><<<cg32, 256, 0, stream>>>(buf0, Pb0c1, b0c1b, buf1);
    conv_mfma_k<256,256,3,1,1,0,32><<<cg32, 256, 0, stream>>>(buf1, Pb0c2, b0c2b, buf2);
    ln_k<<<NB*QLEN/4, 256, 0, stream>>>(buf0, buf2, b0lnw, b0lnb, buf1);

    // ---- block 1 (dil=2)
    conv_mfma_k<256,256,3,2,1,0,32><<<cg32, 256, 0, stream>>>(buf1, Pb1c1, b1c1b, buf0);
    conv_mfma_k<256,256,3,2,1,0,32><<<cg32, 256, 0, stream>>>(buf0, Pb1c2, b1c2b, buf2);
    ln_k<<<NB*QLEN/4, 256, 0, stream>>>(buf1, buf2, b1lnw, b1lnb, buf0);

    // ---- fused output LN + rho/phi: buf0 -> buf1, rhoA, phiA
    ln_rp_k<<<NB*QLEN/4, 256, 0, stream>>>(buf0, olnw, olnb, rpw, rpb,
                                           buf1, rhoA, phiA);

    // ---- Kg (sigmoid GEMM via MFMA)
    conv_mfma_k<256,128,1,1,2,0,32><<<cg32, 256, 0, stream>>>(buf1, Pgain, gainb, Kg);

    // ---- Kalman scan
    kalman_k<<<NB, 64, 0, stream>>>(x_in, Kg, rhoA, phiA, xpost);

    // ---- rollout v7 (cooperative; 128 blocks <= 256 CUs, 1 block/CU by LDS)
    rollout_k7<<<128, 1024, 0, stream>>>(buf1, xpost, riw, rib, wih, whh,
                                         bih, bhh, rlnw, rlnb, rprw, rprb,
                                         zbufp, hrawp, barsp, out);
}

// Round 10
// 1705.557 us; speedup vs baseline: 1.3480x; 1.3480x over previous
//
#include <hip/hip_runtime.h>
#include <math.h>

#define QLEN 512
#define NB   64
#define DD   128
#define HH   256
#define WOUT 64
#define PI_F 3.14159265358979323846f

typedef __attribute__((ext_vector_type(8))) short bf16x8;
typedef __attribute__((ext_vector_type(4))) float f32x4;

__device__ __forceinline__ float sigmf(float x){ return 1.0f/(1.0f+expf(-x)); }
__device__ __forceinline__ float geluf(float x){ return 0.5f*x*(1.0f+erff(x*0.7071067811865476f)); }

// fp32 -> bf16 round-to-nearest-even
__device__ __forceinline__ unsigned short f2bf(float f){
    unsigned u = __float_as_uint(f);
    u += 0x7fffu + ((u >> 16) & 1u);
    return (unsigned short)(u >> 16);
}
__device__ __forceinline__ float bf2f(unsigned short h){
    return __uint_as_float(((unsigned)h) << 16);
}

// ---------------------------------------------------------------------------
// Fused weight-prep (1 launch).
// packw_elem: conv weights -> bf16x3 limbs in MFMA B-frag order.
// fp32 MANDATORY for rollout weights (recurrence amplifies weight noise
// ~2e6x; plain bf16 gave absmax 31). pq_elem packs those as float4.
__device__ __forceinline__ void packw_elem(const float* __restrict__ w,
                                           unsigned short* __restrict__ dst,
                                           int idx, int CIN, int COUT, int KS) {
    int j = idx & 7; int rest = idx >> 3;
    int lane = rest & 63; rest >>= 6;
    int NT = COUT >> 4;
    int nt = rest % NT; int kt = rest / NT;
    int k = kt*32 + (lane >> 4)*8 + j;
    int cout = nt*16 + (lane & 15);
    int tap = k / CIN, ci = k - tap*CIN;
    float v = w[((size_t)cout*CIN + ci)*KS + tap];
    unsigned short h0 = f2bf(v);  float r = v - bf2f(h0);
    unsigned short h1 = f2bf(r);  r -= bf2f(h1);
    unsigned short h2 = f2bf(r);
    int SZ = KS*CIN*COUT;
    dst[idx] = h0; dst[SZ + idx] = h1; dst[2*SZ + idx] = h2;
}
__device__ __forceinline__ void pq_elem(const float* __restrict__ in,
                                        float4* __restrict__ out,
                                        int idx, int R, int C) {
    int r = idx % R, j4 = idx / R;
    const float* p = in + (size_t)r*C + 4*j4;
    float4 v; v.x = p[0]; v.y = p[1]; v.z = p[2]; v.w = p[3];
    out[idx] = v;
}
__global__ __launch_bounds__(256) void prep_k(
    const float* __restrict__ inp_w, const float* __restrict__ b0c1w,
    const float* __restrict__ b0c2w, const float* __restrict__ b1c1w,
    const float* __restrict__ b1c2w, const float* __restrict__ gainw,
    const float* __restrict__ riw,  const float* __restrict__ wih,
    const float* __restrict__ whh,
    unsigned short* __restrict__ Pinp,  unsigned short* __restrict__ Pb0c1,
    unsigned short* __restrict__ Pb0c2, unsigned short* __restrict__ Pb1c1,
    unsigned short* __restrict__ Pb1c2, unsigned short* __restrict__ Pgain,
    float4* __restrict__ Wri4, float4* __restrict__ Wih4, float4* __restrict__ Whh4)
{
    int idx = blockIdx.x*256 + threadIdx.x;
    if      (idx <   98304) packw_elem(inp_w, Pinp,  idx,          384, 256, 1);
    else if (idx <  294912) packw_elem(b0c1w, Pb0c1, idx -  98304, 256, 256, 3);
    else if (idx <  491520) packw_elem(b0c2w, Pb0c2, idx - 294912, 256, 256, 3);
    else if (idx <  688128) packw_elem(b1c1w, Pb1c1, idx - 491520, 256, 256, 3);
    else if (idx <  884736) packw_elem(b1c2w, Pb1c2, idx - 688128, 256, 256, 3);
    else if (idx <  917504) packw_elem(gainw, Pgain, idx - 884736, 256, 128, 1);
    else if (idx <  942080) pq_elem(riw, Wri4, idx - 917504, 256, 384);
    else if (idx <  991232) pq_elem(wih, Wih4, idx - 942080, 768, 256);
    else if (idx < 1040384) pq_elem(whh, Whh4, idx - 991232, 768, 256);
}

// ---------------------------------------------------------------------------
// Conv-as-GEMM via bf16x3 MFMA (6 products = fp32-equivalent). Proven r4:
// passes at absmax 0.125. Unchanged.
template<int CIN, int COUT, int KS, int DIL, int ACT, int FEATS, int TM>
__global__ __launch_bounds__(256, 2) void conv_mfma_k(
    const float* __restrict__ X, const unsigned short* __restrict__ W,
    const float* __restrict__ bias, float* __restrict__ Y)
{
    constexpr int HALO = (KS == 3) ? DIL : 0;
    constexpr int ROWS = TM + 2*HALO;
    constexpr int CINP = CIN + 8;
    constexpr int MF   = TM/16;
    constexpr int NF   = COUT/64;
    constexpr int KT   = (KS*CIN)/32;
    constexpr int TPC  = CIN/32;
    constexpr int WSZ  = KS*CIN*COUT;

    __shared__ __align__(16) unsigned short As[3][ROWS][CINP];

    const int b   = blockIdx.y;
    const int t0  = blockIdx.x * TM;
    const int tid = threadIdx.x;

    if constexpr (FEATS) {
        for (int idx = tid; idx < TM*DD; idx += 256) {
            int r = idx >> 7, d = idx & (DD-1);
            int t = t0 + r;
            const float* xr = X + ((size_t)b*QLEN + t)*DD + d;
            float x    = xr[0];
            float xm1  = (t >= 1) ? xr[-DD]   : 0.f;
            float xm2  = (t >= 2) ? xr[-2*DD] : 0.f;
            float dy   = (t >= 1) ? (x - xm1)   : 0.f;
            float dym1 = (t >= 2) ? (xm1 - xm2) : 0.f;
            float ddy  = (t >= 1) ? (dy - dym1) : 0.f;
            float vals[3] = {x, dy, ddy};
            #pragma unroll
            for (int f = 0; f < 3; ++f) {
                float v = vals[f];
                unsigned short h0 = f2bf(v);  float rr = v - bf2f(h0);
                unsigned short h1 = f2bf(rr); rr -= bf2f(h1);
                unsigned short h2 = f2bf(rr);
                As[0][r][f*DD + d] = h0;
                As[1][r][f*DD + d] = h1;
                As[2][r][f*DD + d] = h2;
            }
        }
    } else {
        for (int idx = tid; idx < ROWS*(CIN/4); idx += 256) {
            int r = idx / (CIN/4), c4 = idx % (CIN/4);
            int gr = t0 + r - HALO;
            gr = gr < 0 ? 0 : (gr > QLEN-1 ? QLEN-1 : gr);
            float4 v = reinterpret_cast<const float4*>(X + ((size_t)b*QLEN + gr)*CIN)[c4];
            float vv[4] = {v.x, v.y, v.z, v.w};
            ushort4 s0, s1, s2;
            unsigned short* q0 = (unsigned short*)&s0;
            unsigned short* q1 = (unsigned short*)&s1;
            unsigned short* q2 = (unsigned short*)&s2;
            #pragma unroll
            for (int e = 0; e < 4; ++e) {
                float v1 = vv[e];
                unsigned short h0 = f2bf(v1);  float rr = v1 - bf2f(h0);
                unsigned short h1 = f2bf(rr);  rr -= bf2f(h1);
                q0[e] = h0; q1[e] = h1; q2[e] = f2bf(rr);
            }
            *reinterpret_cast<ushort4*>(&As[0][r][c4*4]) = s0;
            *reinterpret_cast<ushort4*>(&As[1][r][c4*4]) = s1;
            *reinterpret_cast<ushort4*>(&As[2][r][c4*4]) = s2;
        }
    }
    __syncthreads();

    const int wv = tid >> 6, l = tid & 63;
    const int lr = l & 15, lk = l >> 4;

    f32x4 acc[MF][NF];
    #pragma unroll
    for (int m = 0; m < MF; ++m)
        #pragma unroll
        for (int n = 0; n < NF; ++n)
            #pragma unroll
            for (int i = 0; i < 4; ++i) acc[m][n][i] = 0.f;

    auto loadB = [&](int kt, bf16x8 (&Bf)[NF][3]) {
        #pragma unroll
        for (int n = 0; n < NF; ++n) {
            const unsigned short* p =
                W + ((size_t)(kt*(COUT/16) + wv*NF + n)*64 + l)*8;
            #pragma unroll
            for (int q = 0; q < 3; ++q)
                Bf[n][q] = *reinterpret_cast<const bf16x8*>(p + (size_t)q*WSZ);
        }
    };
    auto comp = [&](int kt, bf16x8 (&Bf)[NF][3]) {
        const int tap = kt / TPC;
        const int kin = (kt % TPC)*32 + lk*8;
        bf16x8 A[MF][3];
        #pragma unroll
        for (int m = 0; m < MF; ++m) {
            const int row = m*16 + lr + tap*DIL;
            #pragma unroll
            for (int q = 0; q < 3; ++q)
                A[m][q] = *reinterpret_cast<const bf16x8*>(&As[q][row][kin]);
        }
        #pragma unroll
        for (int m = 0; m < MF; ++m)
            #pragma unroll
            for (int n = 0; n < NF; ++n) {
                f32x4 c = acc[m][n];
                c = __builtin_amdgcn_mfma_f32_16x16x32_bf16(A[m][0], Bf[n][0], c, 0,0,0);
                c = __builtin_amdgcn_mfma_f32_16x16x32_bf16(A[m][0], Bf[n][1], c, 0,0,0);
                c = __builtin_amdgcn_mfma_f32_16x16x32_bf16(A[m][1], Bf[n][0], c, 0,0,0);
                c = __builtin_amdgcn_mfma_f32_16x16x32_bf16(A[m][0], Bf[n][2], c, 0,0,0);
                c = __builtin_amdgcn_mfma_f32_16x16x32_bf16(A[m][1], Bf[n][1], c, 0,0,0);
                c = __builtin_amdgcn_mfma_f32_16x16x32_bf16(A[m][2], Bf[n][0], c, 0,0,0);
                acc[m][n] = c;
            }
    };

    bf16x8 B0[NF][3], B1[NF][3];
    loadB(0, B0);
    #pragma unroll 1
    for (int kt = 0; kt < KT; kt += 2) {
        loadB(kt+1, B1);
        comp(kt, B0);
        if (kt + 2 < KT) loadB(kt+2, B0);
        comp(kt+1, B1);
    }

    #pragma unroll
    for (int n = 0; n < NF; ++n) {
        const int col = (wv*NF + n)*16 + lr;
        const float bv = bias[col];
        #pragma unroll
        for (int m = 0; m < MF; ++m) {
            #pragma unroll
            for (int i = 0; i < 4; ++i) {
                float v = acc[m][n][i] + bv;
                if constexpr (ACT == 1) v = geluf(v);
                if constexpr (ACT == 2) v = sigmf(v);
                Y[((size_t)b*QLEN + t0 + m*16 + lk*4 + i)*COUT + col] = v;
            }
        }
    }
}

// ---------------------------------------------------------------------------
__global__ __launch_bounds__(256) void ln_k(
    const float* __restrict__ X, const float* __restrict__ R,
    const float* __restrict__ w, const float* __restrict__ b,
    float* __restrict__ Y)
{
    int row  = blockIdx.x*4 + (threadIdx.x >> 6);
    int lane = threadIdx.x & 63;
    float4 v = reinterpret_cast<const float4*>(X + (size_t)row*HH)[lane];
    float4 rv = reinterpret_cast<const float4*>(R + (size_t)row*HH)[lane];
    v.x += rv.x; v.y += rv.y; v.z += rv.z; v.w += rv.w;
    float s = v.x + v.y + v.z + v.w;
    #pragma unroll
    for (int off = 32; off > 0; off >>= 1) s += __shfl_xor(s, off);
    float m = s * (1.0f/HH);
    float dx=v.x-m, dy=v.y-m, dz=v.z-m, dw=v.w-m;
    float q = dx*dx + dy*dy + dz*dz + dw*dw;
    #pragma unroll
    for (int off = 32; off > 0; off >>= 1) q += __shfl_xor(q, off);
    float inv = rsqrtf(q*(1.0f/HH) + 1e-5f);
    float4 wv = reinterpret_cast<const float4*>(w)[lane];
    float4 bv = reinterpret_cast<const float4*>(b)[lane];
    float4 o;
    o.x = dx*inv*wv.x + bv.x;
    o.y = dy*inv*wv.y + bv.y;
    o.z = dz*inv*wv.z + bv.z;
    o.w = dw*inv*wv.w + bv.w;
    reinterpret_cast<float4*>(Y + (size_t)row*HH)[lane] = o;
}

// ---------------------------------------------------------------------------
__global__ __launch_bounds__(256) void ln_rp_k(
    const float* __restrict__ X, const float* __restrict__ w, const float* __restrict__ b,
    const float* __restrict__ rpw, const float* __restrict__ rpb,
    float* __restrict__ Y, float* __restrict__ rho, float* __restrict__ phi)
{
    int row  = blockIdx.x*4 + (threadIdx.x >> 6);
    int lane = threadIdx.x & 63;
    float4 v = reinterpret_cast<const float4*>(X + (size_t)row*HH)[lane];
    float s = v.x + v.y + v.z + v.w;
    #pragma unroll
    for (int off = 32; off > 0; off >>= 1) s += __shfl_xor(s, off);
    float m = s * (1.0f/HH);
    float dx=v.x-m, dy=v.y-m, dz=v.z-m, dw=v.w-m;
    float q = dx*dx + dy*dy + dz*dz + dw*dw;
    #pragma unroll
    for (int off = 32; off > 0; off >>= 1) q += __shfl_xor(q, off);
    float inv = rsqrtf(q*(1.0f/HH) + 1e-5f);
    float4 wv = reinterpret_cast<const float4*>(w)[lane];
    float4 bv = reinterpret_cast<const float4*>(b)[lane];
    float4 o;
    o.x = dx*inv*wv.x + bv.x;
    o.y = dy*inv*wv.y + bv.y;
    o.z = dz*inv*wv.z + bv.z;
    o.w = dw*inv*wv.w + bv.w;
    reinterpret_cast<float4*>(Y + (size_t)row*HH)[lane] = o;

    float4 w0 = reinterpret_cast<const float4*>(rpw)[lane];
    float4 w1 = reinterpret_cast<const float4*>(rpw + HH)[lane];
    float d0 = o.x*w0.x + o.y*w0.y + o.z*w0.z + o.w*w0.w;
    float d1 = o.x*w1.x + o.y*w1.y + o.z*w1.z + o.w*w1.w;
    #pragma unroll
    for (int off = 32; off > 0; off >>= 1) { d0 += __shfl_xor(d0, off); d1 += __shfl_xor(d1, off); }
    if (lane == 0) {
        rho[row] = 1.25f * sigmf(d0 + rpb[0]);
        phi[row] = PI_F * tanhf(d1 + rpb[1]);
    }
}

// ---------------------------------------------------------------------------
__global__ __launch_bounds__(64) void kalman_k(
    const float* __restrict__ Xin, const float* __restrict__ Kg,
    const float* __restrict__ rho_a, const float* __restrict__ phi_a,
    float* __restrict__ xpost)
{
    int b = blockIdx.x, l = threadIdx.x;
    const float* xb = Xin + (size_t)b*QLEN*DD;
    float re = xb[l], im = xb[64 + l];

    float rho_c = rho_a[b*QLEN], phi_c = phi_a[b*QLEN];
    const float* kg0 = Kg + (size_t)b*QLEN*DD;
    float kr_c = kg0[l], ki_c = kg0[64 + l];
    float y0_c = xb[l],  y1_c = xb[64 + l];

    for (int t = 0; t < QLEN; ++t) {
        float rho_n = 0.f, phi_n = 0.f, kr_n = 0.f, ki_n = 0.f, y0_n = 0.f, y1_n = 0.f;
        if (t + 1 < QLEN) {
            rho_n = rho_a[b*QLEN + t + 1];
            phi_n = phi_a[b*QLEN + t + 1];
            const float* kg = Kg + ((size_t)b*QLEN + t + 1)*DD;
            const float* yr = xb + (size_t)(t + 1)*DD;
            kr_n = kg[l]; ki_n = kg[64 + l];
            y0_n = yr[l]; y1_n = yr[64 + l];
        }
        float sn, cs; sincosf(phi_c, &sn, &cs);
        float pr = rho_c*(cs*re - sn*im);
        float pi = rho_c*(sn*re + cs*im);
        re = pr + kr_c*(y0_c - pr);
        im = pi + ki_c*(y1_c - pi);
        rho_c = rho_n; phi_c = phi_n; kr_c = kr_n; ki_c = ki_n; y0_c = y0_n; y1_c = y1_n;
    }
    xpost[b*DD + l]      = re;
    xpost[b*DD + 64 + l] = im;
}

// ---------------------------------------------------------------------------
// Rollout v5 (r4-proven: 1058us, per-CU L2-port roofline at 119 GB/s/CU on
// the 1.97 MB/step fp32 weight stream). fp32 precision-mandatory.
// r8 LESSON: cooperative multi-block (k7, LDS-resident weight slices +
// agent-scope ticket barriers) PASSED but ran 1617us steady + 42ms first
// dispatch. Agent-scope acquire/release forces per-XCD L2 inv/writeback each
// barrier -> exchange resolves through L3, ~23us/step sync overhead.
// Per-step cross-block sync costs >=10-20us/step on this chip — cooperative
// rollout is dead. Do not re-attempt. bf16 compression also dead (absmax 31);
// bf16x3 = 6B/elem > fp32. This is the rollout floor.
__device__ __forceinline__ float bsum16(float v, float* red) {
    #pragma unroll
    for (int off = 32; off > 0; off >>= 1) v += __shfl_xor(v, off);
    __syncthreads();
    if ((threadIdx.x & 63) == 0) red[threadIdx.x >> 6] = v;
    __syncthreads();
    float s = 0.f;
    #pragma unroll
    for (int i = 0; i < 16; ++i) s += red[i];
    return s;
}
__device__ __forceinline__ float2 bsum16_2(float a, float b, float* red) {
    #pragma unroll
    for (int off = 32; off > 0; off >>= 1) { a += __shfl_xor(a, off); b += __shfl_xor(b, off); }
    __syncthreads();
    if ((threadIdx.x & 63) == 0) { red[threadIdx.x >> 6] = a; red[16 + (threadIdx.x >> 6)] = b; }
    __syncthreads();
    float sa = 0.f, sb = 0.f;
    #pragma unroll
    for (int i = 0; i < 16; ++i) { sa += red[i]; sb += red[16 + i]; }
    float2 r; r.x = sa; r.y = sb; return r;
}

__global__ __launch_bounds__(1024) void rollout_k5(
    const float* __restrict__ Hs, const float* __restrict__ xpost,
    const float4* __restrict__ Wri4,
    const float* __restrict__ rib,
    const float4* __restrict__ Wih4,
    const float4* __restrict__ Whh4,
    const float* __restrict__ bih, const float* __restrict__ bhh,
    const float* __restrict__ lnw, const float* __restrict__ lnb,
    const float* __restrict__ rpw, const float* __restrict__ rpb,
    float* __restrict__ out)
{
    __shared__ __align__(16) float hc[384];
    __shared__ __align__(16) float zsh[256];
    __shared__ float zpart[4][256];
    __shared__ float gpart[6][4][256];
    __shared__ float red[32];

    const int tid = threadIdx.x;
    const int o = tid & 255, p = tid >> 8;
    const int b = blockIdx.x;

    if (p == 0) hc[o] = Hs[((size_t)b*QLEN + QLEN-1)*HH + o];
    if (p == 1 && o < DD) hc[HH + o] = xpost[b*DD + o];

    const float bi0 = bih[o],    bi1 = bih[HH+o], bi2 = bih[2*HH+o];
    const float bh0 = bhh[o],    bh1 = bhh[HH+o], bh2 = bhh[2*HH+o];
    const float rb  = rib[o];
    const float lw  = lnw[o],    lb  = lnb[o];
    const float rw0 = rpw[o],    rw1 = rpw[HH+o];
    const float rpb0 = rpb[0],   rpb1 = rpb[1];
    const float4* hc4 = reinterpret_cast<const float4*>(hc);
    const float4* zf4 = reinterpret_cast<const float4*>(zsh);
    __syncthreads();

    for (int s = 0; s < WOUT; ++s) {
        float az = 0.f;
        {
            const float4* wp = Wri4 + (size_t)(p*24)*256 + o;
            #pragma unroll 8
            for (int j4 = 0; j4 < 24; ++j4) {
                float4 w = wp[(size_t)j4*256];
                float4 h = hc4[p*24 + j4];
                az = fmaf(w.x, h.x, az); az = fmaf(w.y, h.y, az);
                az = fmaf(w.z, h.z, az); az = fmaf(w.w, h.w, az);
            }
        }
        float e0=0.f, e1=0.f, e2=0.f;
        {
            const float4* whp = Whh4 + (size_t)(p*16)*768 + o;
            #pragma unroll 4
            for (int j4 = 0; j4 < 16; ++j4) {
                float4 h = hc4[p*16 + j4];
                float4 wd = whp[(size_t)j4*768];
                float4 we = whp[(size_t)j4*768 + 256];
                float4 wf = whp[(size_t)j4*768 + 512];
                e0 = fmaf(wd.x,h.x,e0); e0 = fmaf(wd.y,h.y,e0); e0 = fmaf(wd.z,h.z,e0); e0 = fmaf(wd.w,h.w,e0);
                e1 = fmaf(we.x,h.x,e1); e1 = fmaf(we.y,h.y,e1); e1 = fmaf(we.z,h.z,e1); e1 = fmaf(we.w,h.w,e1);
                e2 = fmaf(wf.x,h.x,e2); e2 = fmaf(wf.y,h.y,e2); e2 = fmaf(wf.z,h.z,e2); e2 = fmaf(wf.w,h.w,e2);
            }
        }
        zpart[p][o] = az;
        gpart[3][p][o]=e0; gpart[4][p][o]=e1; gpart[5][p][o]=e2;
        __syncthreads();
        if (p == 0)
            zsh[o] = tanhf(zpart[0][o]+zpart[1][o]+zpart[2][o]+zpart[3][o] + rb);
        __syncthreads();

        float g0=0.f, g1=0.f, g2=0.f;
        {
            const float4* wip = Wih4 + (size_t)(p*16)*768 + o;
            #pragma unroll 4
            for (int j4 = 0; j4 < 16; ++j4) {
                float4 z = zf4[p*16 + j4];
                float4 wa = wip[(size_t)j4*768];
                float4 wb = wip[(size_t)j4*768 + 256];
                float4 wc = wip[(size_t)j4*768 + 512];
                g0 = fmaf(wa.x,z.x,g0); g0 = fmaf(wa.y,z.y,g0); g0 = fmaf(wa.z,z.z,g0); g0 = fmaf(wa.w,z.w,g0);
                g1 = fmaf(wb.x,z.x,g1); g1 = fmaf(wb.y,z.y,g1); g1 = fmaf(wb.z,z.z,g1); g1 = fmaf(wb.w,z.w,g1);
                g2 = fmaf(wc.x,z.x,g2); g2 = fmaf(wc.y,z.y,g2); g2 = fmaf(wc.z,z.z,g2); g2 = fmaf(wc.w,z.w,g2);
            }
        }
        gpart[0][p][o]=g0; gpart[1][p][o]=g1; gpart[2][p][o]=g2;
        __syncthreads();

        float go = 0.f;
        if (p == 0) {
            float G0 = gpart[0][0][o]+gpart[0][1][o]+gpart[0][2][o]+gpart[0][3][o] + bi0;
            float G1 = gpart[1][0][o]+gpart[1][1][o]+gpart[1][2][o]+gpart[1][3][o] + bi1;
            float G2 = gpart[2][0][o]+gpart[2][1][o]+gpart[2][2][o]+gpart[2][3][o] + bi2;
            float E0 = gpart[3][0][o]+gpart[3][1][o]+gpart[3][2][o]+gpart[3][3][o] + bh0;
            float E1 = gpart[4][0][o]+gpart[4][1][o]+gpart[4][2][o]+gpart[4][3][o] + bh1;
            float E2 = gpart[5][0][o]+gpart[5][1][o]+gpart[5][2][o]+gpart[5][3][o] + bh2;
            float r  = sigmf(G0 + E0);
            float zg = sigmf(G1 + E1);
            float n  = tanhf(G2 + r*E2);
            go = (1.0f - zg)*n + zg*hc[o];
        }

        float m   = bsum16(go, red) * (1.0f/HH);
        float d   = (p == 0) ? (go - m) : 0.f;
        float var = bsum16(d*d, red) * (1.0f/HH);
        float hn  = (p == 0) ? (d * rsqrtf(var + 1e-5f) * lw + lb) : 0.f;

        float2 ps = bsum16_2((p == 0) ? hn*rw0 : 0.f, (p == 0) ? hn*rw1 : 0.f, red);
        float rho = 1.25f * sigmf(ps.x + rpb0);
        float phi = PI_F * tanhf(ps.y + rpb1);
        float sn, cs; sincosf(phi, &sn, &cs);

        if (p == 0) hc[o] = hn;
        if (tid < 64) {
            float cre = hc[HH + tid], cim = hc[HH + 64 + tid];
            float nr = rho*(cs*cre - sn*cim);
            float ni = rho*(sn*cre + cs*cim);
            hc[HH + tid] = nr; hc[HH + 64 + tid] = ni;
            float* ob = out + ((size_t)b*WOUT + s)*DD;
            ob[tid] = nr; ob[64 + tid] = ni;
        }
        __syncthreads();
    }
}

// ---------------------------------------------------------------------------
extern "C" void kernel_launch(void* const* d_in, const int* in_sizes, int n_in,
                              void* d_out, int out_size, void* d_ws, size_t ws_size,
                              hipStream_t stream)
{
    const float* x_in   = (const float*)d_in[0];
    const float* inp_w  = (const float*)d_in[2];
    const float* inp_b  = (const float*)d_in[3];
    const float* b0c1w  = (const float*)d_in[4];
    const float* b0c1b  = (const float*)d_in[5];
    const float* b0c2w  = (const float*)d_in[6];
    const float* b0c2b  = (const float*)d_in[7];
    const float* b0lnw  = (const float*)d_in[8];
    const float* b0lnb  = (const float*)d_in[9];
    const float* b1c1w  = (const float*)d_in[10];
    const float* b1c1b  = (const float*)d_in[11];
    const float* b1c2w  = (const float*)d_in[12];
    const float* b1c2b  = (const float*)d_in[13];
    const float* b1lnw  = (const float*)d_in[14];
    const float* b1lnb  = (const float*)d_in[15];
    const float* olnw   = (const float*)d_in[16];
    const float* olnb   = (const float*)d_in[17];
    const float* gainw  = (const float*)d_in[18];
    const float* gainb  = (const float*)d_in[19];
    const float* rpw    = (const float*)d_in[20];
    const float* rpb    = (const float*)d_in[21];
    const float* riw    = (const float*)d_in[22];
    const float* rib    = (const float*)d_in[23];
    const float* wih    = (const float*)d_in[24];
    const float* whh    = (const float*)d_in[25];
    const float* bih    = (const float*)d_in[26];
    const float* bhh    = (const float*)d_in[27];
    const float* rlnw   = (const float*)d_in[28];
    const float* rlnb   = (const float*)d_in[29];
    const float* rprw   = (const float*)d_in[30];
    const float* rprb   = (const float*)d_in[31];
    float* out = (float*)d_out;

    // workspace layout (floats)
    float* ws   = (float*)d_ws;
    float* buf0 = ws;                    // 8388608
    float* buf1 = ws +  8388608;         // 8388608
    float* buf2 = ws + 16777216;         // 8388608
    float* Kg    = buf2;                 // 4194304 (buf2 dead by then)
    float* rhoA  = buf2 + 4194304;       // 32768
    float* phiA  = rhoA + 32768;         // 32768
    float* xpost = phiA + 32768;         // 8192
    float* wts   = ws + 25165824;
    // bf16x3 packed conv weights (ushort counts):
    unsigned short* Pinp  = (unsigned short*)wts;   // 3*98304  = 294912
    unsigned short* Pb0c1 = Pinp  + 294912;         // 3*196608 = 589824
    unsigned short* Pb0c2 = Pb0c1 + 589824;
    unsigned short* Pb1c1 = Pb0c2 + 589824;
    unsigned short* Pb1c2 = Pb1c1 + 589824;
    unsigned short* Pgain = Pb1c2 + 589824;         // 3*32768 = 98304
    // fp32 rollout packs after (16B-aligned: offset 26542080 floats):
    float4* Wri4 = (float4*)(wts + 1376256);        // 24576 float4
    float4* Wih4 = (float4*)(wts + 1376256 +  98304);  // 49152 float4
    float4* Whh4 = (float4*)(wts + 1376256 + 294912);  // 49152 float4
    // total ws use: 27033600 floats ~= 103.1 MB

    // ---- fused weight prep (1 launch)
    prep_k<<<4064, 256, 0, stream>>>(inp_w, b0c1w, b0c2w, b1c1w, b1c2w, gainw,
                                     riw, wih, whh,
                                     Pinp, Pb0c1, Pb0c2, Pb1c1, Pb1c2, Pgain,
                                     Wri4, Wih4, Whh4);

    dim3 cg16(QLEN/16, NB);
    dim3 cg32(QLEN/32, NB);

    // ---- input projection (feats built on the fly): x_in -> buf0
    conv_mfma_k<384,256,1,1,0,1,16><<<cg16, 256, 0, stream>>>(x_in, Pinp, inp_b, buf0);

    // ---- block 0 (dil=1)
    conv_mfma_k<256,256,3,1,1,0,32><<<cg32, 256, 0, stream>>>(buf0, Pb0c1, b0c1b, buf1);
    conv_mfma_k<256,256,3,1,1,0,32><<<cg32, 256, 0, stream>>>(buf1, Pb0c2, b0c2b, buf2);
    ln_k<<<NB*QLEN/4, 256, 0, stream>>>(buf0, buf2, b0lnw, b0lnb, buf1);

    // ---- block 1 (dil=2)
    conv_mfma_k<256,256,3,2,1,0,32><<<cg32, 256, 0, stream>>>(buf1, Pb1c1, b1c1b, buf0);
    conv_mfma_k<256,256,3,2,1,0,32><<<cg32, 256, 0, stream>>>(buf0, Pb1c2, b1c2b, buf2);
    ln_k<<<NB*QLEN/4, 256, 0, stream>>>(buf1, buf2, b1lnw, b1lnb, buf0);

    // ---- fused output LN + rho/phi: buf0 -> buf1, rhoA, phiA
    ln_rp_k<<<NB*QLEN/4, 256, 0, stream>>>(buf0, olnw, olnb, rpw, rpb,
                                           buf1, rhoA, phiA);

    // ---- Kg (sigmoid GEMM via MFMA)
    conv_mfma_k<256,128,1,1,2,0,32><<<cg32, 256, 0, stream>>>(buf1, Pgain, gainb, Kg);

    // ---- Kalman scan
    kalman_k<<<NB, 64, 0, stream>>>(x_in, Kg, rhoA, phiA, xpost);

    // ---- rollout v5 (fp32 precision-mandatory; per-CU L2-port roofline)
    rollout_k5<<<NB, 1024, 0, stream>>>(buf1, xpost, Wri4, rib, Wih4, Whh4,
                                        bih, bhh, rlnw, rlnb, rprw, rprb, out);
}